// Round 8
// baseline (101.694 us; speedup 1.0000x reference)
//
#include <hip/hip_runtime.h>
#include <math.h>

// ---------------------------------------------------------------------------
// AttentiveFPModule: knn(K=3) attentive interpolate + concat + Linear + BN + LeakyReLU
// Sizes: Nx=4096, Ny=16384, C=256, Cs=128, Co=256, B=4, Kin=384
// 4 launches:
//   k_prep : attv/pos4/Bbuf fragments/start/counter/tail outputs
//   k_knn  : knn scan (LDS-staged) + fused gather -> Abuf (MFMA A-fragments)
//   k_gemm : coalesced Abuf reads -> MFMA -> h(+bias) -> last-block BN stats
//   k_final: BN apply + LeakyReLU in place
// Lesson R7: never co-locate the scattered gather with the 1-wave/SIMD MFMA
// kernel; the gather needs occupancy (k_knn has 16 waves/CU).
// ---------------------------------------------------------------------------

#define KNEI 3
#define GL 16           // lanes per y-point in k_knn
#define UNR 4           // scan unroll
#define KCAP 2048       // staged pos4 capacity (float4s)
#define CIN 256         // C
#define CSK 128         // Cs
#define CO  256         // Co
#define NKS 12          // Kin / 32
#define NNT 16          // Co / 16
#define NYF 16384.0f
#define NPOS4 12288     // Ny*3/4
#define NTAIL4 16384    // NPOS4 + Ny/4

typedef __attribute__((ext_vector_type(8))) short bf16x8;
typedef __attribute__((ext_vector_type(4))) float f32x4;

__device__ __forceinline__ ushort f2bf(float f) {
    unsigned u = __float_as_uint(f);
    u += 0x7fffu + ((u >> 16) & 1u);
    return (ushort)(u >> 16);
}

__device__ __forceinline__ bool nless(float da, int ia, float db, int ib) {
    return (da < db) || (da == db && ia < ib);
}

__device__ __forceinline__ void ins3f(float dd, int j,
                                      float& d0, int& i0,
                                      float& d1, int& i1,
                                      float& d2, int& i2) {
    bool l0 = dd < d0;
    bool l1 = dd < d1;
    bool l2 = dd < d2;
    float n2 = l1 ? d1 : (l2 ? dd : d2); int m2 = l1 ? i1 : (l2 ? j : i2);
    float n1 = l0 ? d0 : (l1 ? dd : d1); int m1 = l0 ? i0 : (l1 ? j : i1);
    float n0 = l0 ? dd : d0;             int m0 = l0 ? j  : i0;
    d0 = n0; i0 = m0; d1 = n1; i1 = m1; d2 = n2; i2 = m2;
}

__device__ __forceinline__ void ins3t(float dd, int j,
                                      float& d0, int& i0,
                                      float& d1, int& i1,
                                      float& d2, int& i2) {
    bool l0 = nless(dd, j, d0, i0);
    bool l1 = nless(dd, j, d1, i1);
    bool l2 = nless(dd, j, d2, i2);
    float n2 = l1 ? d1 : (l2 ? dd : d2); int m2 = l1 ? i1 : (l2 ? j : i2);
    float n1 = l0 ? d0 : (l1 ? dd : d1); int m1 = l0 ? i0 : (l1 ? j : i1);
    float n0 = l0 ? dd : d0;             int m0 = l0 ? j  : i0;
    d0 = n0; i0 = m0; d1 = n1; i1 = m1; d2 = n2; i2 = m2;
}

// K1 (multi-role by block range):
//   [0, Nx/4)         : attv[j] = x[j].w_att ; pos4[j] = (pos, |pos|^2)
//   [Nx/4, Nx/4+48)   : W1 -> Bbuf MFMA B-fragments (bf16)
//   Nx/4+48           : start[] lower bounds; pos4 pad; counter = 0
//   [Nx/4+49, +49+64) : tail outputs (pos_skip copy, batch_skip as float)
__global__ void k_prep(const float* __restrict__ x, const float* __restrict__ pos,
                       const float* __restrict__ w_att, const float* __restrict__ W1,
                       const int* __restrict__ batch,
                       float* __restrict__ attv, float4* __restrict__ pos4,
                       uint4* __restrict__ Bbuf, int* __restrict__ start,
                       int* __restrict__ counter,
                       const float4* __restrict__ pos_skip4,
                       const int4* __restrict__ batch4,
                       float4* __restrict__ out_tail4,
                       int Nx, int NB) {
    int nb_x = Nx >> 2;
    int bid = blockIdx.x;
    int wave = threadIdx.x >> 6;
    int lane = threadIdx.x & 63;

    if (bid < nb_x) {
        int wid = bid * 4 + wave;
        float s = 0.f;
        for (int k = lane * 4; k < CIN; k += 256) {
            float4 xv = *reinterpret_cast<const float4*>(x + (size_t)wid * CIN + k);
            float4 wv = *reinterpret_cast<const float4*>(w_att + k);
            s += xv.x * wv.x + xv.y * wv.y + xv.z * wv.z + xv.w * wv.w;
        }
        #pragma unroll
        for (int off = 32; off; off >>= 1) s += __shfl_xor(s, off);
        if (lane == 0) {
            attv[wid] = s;
            float px = pos[wid * 3], py = pos[wid * 3 + 1], pz = pos[wid * 3 + 2];
            pos4[wid] = make_float4(px, py, pz, px * px + py * py + pz * pz);
        }
        return;
    }
    if (bid < nb_x + 48) {
        // Bbuf[(ks*16+nt)*64 + lane] = 8 bf16: elem j = W1[ks*32+(lane>>4)*8+j][nt*16+(lane&15)]
        int p  = (bid - nb_x) * 4 + wave;      // 0..191
        int ks = p >> 4, nt = p & 15;
        int kb = ks * 32 + (lane >> 4) * 8;
        int n  = nt * 16 + (lane & 15);
        ushort u[8];
        #pragma unroll
        for (int j = 0; j < 8; ++j)
            u[j] = f2bf(W1[(size_t)(kb + j) * CO + n]);
        uint4 o;
        o.x = (unsigned)u[0] | ((unsigned)u[1] << 16);
        o.y = (unsigned)u[2] | ((unsigned)u[3] << 16);
        o.z = (unsigned)u[4] | ((unsigned)u[5] << 16);
        o.w = (unsigned)u[6] | ((unsigned)u[7] << 16);
        Bbuf[(size_t)(ks * 16 + nt) * 64 + lane] = o;
        return;
    }
    if (bid == nb_x + 48) {
        int t = threadIdx.x;
        if (t < 64) {
            int b = t;
            if (b > NB) return;
            int lo = 0, hi = Nx;
            while (lo < hi) {
                int mid = (lo + hi) >> 1;
                if (batch[mid] < b) lo = mid + 1; else hi = mid;
            }
            start[b] = lo;
        } else if (t < 128) {
            pos4[Nx + (t - 64)] = make_float4(0.f, 0.f, 0.f, 0.f);
        } else if (t == 128) {
            *counter = 0;
        }
        return;
    }
    // tail outputs
    int gid = (bid - (nb_x + 49)) * 256 + threadIdx.x;
    if (gid < NPOS4) {
        out_tail4[gid] = pos_skip4[gid];
    } else if (gid < NTAIL4) {
        int4 b4 = batch4[gid - NPOS4];
        out_tail4[gid] = make_float4((float)b4.x, (float)b4.y, (float)b4.z, (float)b4.w);
    }
}

// K2: 16 y-points per block (16 lanes each). knn scan (LDS-staged pos4
// segment) -> butterfly (all lanes get top-3) -> coef -> fused gather:
// block writes its 16 rows of A=[y||x_skip] into Abuf in MFMA A-fragment
// layout (bf16). 1024 blocks -> 16 waves/CU hides the scattered-gather latency.
__global__ __launch_bounds__(256) void k_knn(
                      const float4* __restrict__ pos4,
                      const float* __restrict__ attv,
                      const float* __restrict__ pos_skip,
                      const int* __restrict__ batch_skip,
                      const int* __restrict__ start,
                      const float* __restrict__ x,
                      const float* __restrict__ x_skip,
                      uint4* __restrict__ Abuf, int Ny) {
    __shared__ float4 seg[KCAP + 64];
    __shared__ float coefL[16][3];
    __shared__ int   idxL[16][3];
    const int tid = threadIdx.x;
    int i16 = tid >> 4;
    int i   = blockIdx.x * 16 + i16;
    int sub = tid & (GL - 1);

    float py0 = pos_skip[i * 3], py1 = pos_skip[i * 3 + 1], py2 = pos_skip[i * 3 + 2];
    int bb = batch_skip[i];
    int s = start[bb], e = start[bb + 1];
    float ysq = py0 * py0 + py1 * py1 + py2 * py2;

    // block-uniform staging decision
    int b_first = batch_skip[blockIdx.x * 16];
    int b_last  = batch_skip[blockIdx.x * 16 + 15];
    int s0 = start[b_first];
    int span = start[b_last + 1] - s0;
    bool staged = (span <= KCAP);
    if (staged) {
        for (int t = tid; t < span; t += 256) seg[t] = pos4[s0 + t];
        __syncthreads();
    }

    const float FBIG = 3.38e38f;
    float a0 = __int_as_float(0x7f800000), a1 = a0, a2 = a0;
    float b0 = a0, b1v = a0, b2 = a0;
    int   ia0 = 0x7fffffff, ia1 = 0x7fffffff, ia2 = 0x7fffffff;
    int   ib0 = 0x7fffffff, ib1 = 0x7fffffff, ib2 = 0x7fffffff;

    if (staged) {
        for (int jb = s + sub; jb < e; jb += GL * UNR) {
            int j0 = jb, j1 = jb + GL, j2 = jb + 2 * GL, j3 = jb + 3 * GL;
            float4 v0 = seg[j0 - s0];
            float4 v1 = seg[j1 - s0];
            float4 v2 = seg[j2 - s0];
            float4 v3 = seg[j3 - s0];
            float t0 = fmaf(py2, v0.z, fmaf(py1, v0.y, py0 * v0.x));
            float t1 = fmaf(py2, v1.z, fmaf(py1, v1.y, py0 * v1.x));
            float t2 = fmaf(py2, v2.z, fmaf(py1, v2.y, py0 * v2.x));
            float t3 = fmaf(py2, v3.z, fmaf(py1, v3.y, py0 * v3.x));
            float dd0 = fmaf(-2.f, t0, ysq + v0.w);
            float dd1 = fmaf(-2.f, t1, ysq + v1.w);
            float dd2 = fmaf(-2.f, t2, ysq + v2.w);
            float dd3 = fmaf(-2.f, t3, ysq + v3.w);
            dd1 = (j1 < e) ? dd1 : FBIG;
            dd2 = (j2 < e) ? dd2 : FBIG;
            dd3 = (j3 < e) ? dd3 : FBIG;
            ins3f(dd0, j0, a0, ia0, a1, ia1, a2, ia2);
            ins3f(dd1, j1, b0, ib0, b1v, ib1, b2, ib2);
            ins3f(dd2, j2, a0, ia0, a1, ia1, a2, ia2);
            ins3f(dd3, j3, b0, ib0, b1v, ib1, b2, ib2);
        }
    } else {
        for (int jb = s + sub; jb < e; jb += GL * UNR) {
            int j0 = jb, j1 = jb + GL, j2 = jb + 2 * GL, j3 = jb + 3 * GL;
            float4 v0 = pos4[j0];
            float4 v1 = pos4[j1];
            float4 v2 = pos4[j2];
            float4 v3 = pos4[j3];
            float t0 = fmaf(py2, v0.z, fmaf(py1, v0.y, py0 * v0.x));
            float t1 = fmaf(py2, v1.z, fmaf(py1, v1.y, py0 * v1.x));
            float t2 = fmaf(py2, v2.z, fmaf(py1, v2.y, py0 * v2.x));
            float t3 = fmaf(py2, v3.z, fmaf(py1, v3.y, py0 * v3.x));
            float dd0 = fmaf(-2.f, t0, ysq + v0.w);
            float dd1 = fmaf(-2.f, t1, ysq + v1.w);
            float dd2 = fmaf(-2.f, t2, ysq + v2.w);
            float dd3 = fmaf(-2.f, t3, ysq + v3.w);
            dd1 = (j1 < e) ? dd1 : FBIG;
            dd2 = (j2 < e) ? dd2 : FBIG;
            dd3 = (j3 < e) ? dd3 : FBIG;
            ins3f(dd0, j0, a0, ia0, a1, ia1, a2, ia2);
            ins3f(dd1, j1, b0, ib0, b1v, ib1, b2, ib2);
            ins3f(dd2, j2, a0, ia0, a1, ia1, a2, ia2);
            ins3f(dd3, j3, b0, ib0, b1v, ib1, b2, ib2);
        }
    }

    ins3t(b0, ib0, a0, ia0, a1, ia1, a2, ia2);
    ins3t(b1v, ib1, a0, ia0, a1, ia1, a2, ia2);
    ins3t(b2, ib2, a0, ia0, a1, ia1, a2, ia2);

    #pragma unroll
    for (int off = 1; off < GL; off <<= 1) {
        float e0 = __shfl_xor(a0, off), e1 = __shfl_xor(a1, off), e2 = __shfl_xor(a2, off);
        int   j0 = __shfl_xor(ia0, off), j1 = __shfl_xor(ia1, off), j2 = __shfl_xor(ia2, off);
        ins3t(e0, j0, a0, ia0, a1, ia1, a2, ia2);
        ins3t(e1, j1, a0, ia0, a1, ia1, a2, ia2);
        ins3t(e2, j2, a0, ia0, a1, ia1, a2, ia2);
    }

    if (sub == 0) {
        int   jj[3] = { ia0, ia1, ia2 };
        float w[3], a[3];
        #pragma unroll
        for (int t = 0; t < KNEI; ++t) {
            int j = (jj[t] == 0x7fffffff) ? 0 : jj[t];
            jj[t] = j;
            float4 v = pos4[j];
            float dx = v.x - py0;
            float dy = v.y - py1;
            float dz = v.z - py2;
            float sqd = dx * dx + dy * dy + dz * dz;
            w[t] = 1.f / fmaxf(sqd, 1e-16f);
            a[t] = attv[j];
        }
        float m  = fmaxf(a[0], fmaxf(a[1], a[2]));
        float e0s = expf(a[0] - m), e1s = expf(a[1] - m), e2s = expf(a[2] - m);
        float se  = e0s + e1s + e2s;
        float den = w[0] + w[1] + w[2];
        float inv = 1.f / (se * den);
        #pragma unroll
        for (int t = 0; t < KNEI; ++t) {
            idxL[i16][t]  = jj[t];
            coefL[i16][t] = w[t] * ((t == 0) ? e0s : (t == 1) ? e1s : e2s) * inv;
        }
    }
    __syncthreads();

    // ---- fused gather: write this block's 16 rows as A-fragments ----
    // thread t handles row16 = t&15, combos cidx = (t>>4) + 16u, u=0..2.
    // Abuf[(blk*NKS+ks)*64 + row16 + 16*kg] elem j = A[row][ks*32+kg*8+j],
    // ks = cidx>>2, kg = cidx&3, k0 = cidx*8.
    {
        const int row16 = tid & 15, p = tid >> 4;
        const int grow = blockIdx.x * 16 + row16;
        const int g0 = idxL[row16][0];
        const int g1 = idxL[row16][1];
        const int g2 = idxL[row16][2];
        const float c0 = coefL[row16][0];
        const float c1 = coefL[row16][1];
        const float c2 = coefL[row16][2];
        #pragma unroll
        for (int u = 0; u < 3; ++u) {
            const int cidx = p + 16 * u;        // 0..47
            const int k0 = cidx * 8;
            float v[8];
            if (k0 < CIN) {
                const float4* p0 = reinterpret_cast<const float4*>(x + (size_t)g0 * CIN + k0);
                const float4* p1 = reinterpret_cast<const float4*>(x + (size_t)g1 * CIN + k0);
                const float4* p2 = reinterpret_cast<const float4*>(x + (size_t)g2 * CIN + k0);
                #pragma unroll
                for (int h = 0; h < 2; ++h) {
                    float4 a = p0[h], b = p1[h], c = p2[h];
                    v[h * 4 + 0] = c0 * a.x + c1 * b.x + c2 * c.x;
                    v[h * 4 + 1] = c0 * a.y + c1 * b.y + c2 * c.y;
                    v[h * 4 + 2] = c0 * a.z + c1 * b.z + c2 * c.z;
                    v[h * 4 + 3] = c0 * a.w + c1 * b.w + c2 * c.w;
                }
            } else {
                const float4* ps = reinterpret_cast<const float4*>(
                    x_skip + (size_t)grow * CSK + (k0 - CIN));
                #pragma unroll
                for (int h = 0; h < 2; ++h) {
                    float4 a = ps[h];
                    v[h * 4 + 0] = a.x; v[h * 4 + 1] = a.y;
                    v[h * 4 + 2] = a.z; v[h * 4 + 3] = a.w;
                }
            }
            ushort uu[8];
            #pragma unroll
            for (int j = 0; j < 8; ++j) uu[j] = f2bf(v[j]);
            uint4 o;
            o.x = (unsigned)uu[0] | ((unsigned)uu[1] << 16);
            o.y = (unsigned)uu[2] | ((unsigned)uu[3] << 16);
            o.z = (unsigned)uu[4] | ((unsigned)uu[5] << 16);
            o.w = (unsigned)uu[6] | ((unsigned)uu[7] << 16);
            const int ks = cidx >> 2, kg = cidx & 3;
            Abuf[((size_t)blockIdx.x * NKS + ks) * 64 + row16 + 16 * kg] = o;
        }
    }
}

// K3: h = A @ W1 + b1 via bf16 MFMA; A-frags coalesced from Abuf; B
// double-buffered in LDS; +bias; h write; per-block BN partials; the last
// block to finish reduces partials into scale/shift.
__global__ __launch_bounds__(256) void k_gemm(
    const uint4* __restrict__ Abuf, const uint4* __restrict__ Bbuf,
    const float* __restrict__ b1,
    const float* __restrict__ gamma, const float* __restrict__ beta,
    float* __restrict__ hbuf, float* __restrict__ psum, float* __restrict__ psq,
    float* __restrict__ sscale, int* __restrict__ counter) {
    __shared__ uint4 Bls[2][1024];   // 32 KB
    __shared__ float SQ[8][256];     // 8 KB
    __shared__ int lastFlag;
    const int tid = threadIdx.x;
    const int wave = tid >> 6, lane = tid & 63;
    const int blk = blockIdx.x;
    const int strip = blk * 4 + wave;

    f32x4 acc[NNT];
    #pragma unroll
    for (int nt = 0; nt < NNT; ++nt) acc[nt] = (f32x4)(0.f);

    #pragma unroll
    for (int u = 0; u < 4; ++u) Bls[0][tid + 256 * u] = Bbuf[tid + 256 * u];
    __syncthreads();

    #pragma unroll
    for (int ks = 0; ks < NKS; ++ks) {
        const int cur = ks & 1;
        uint4 st[4];
        if (ks < NKS - 1) {
            #pragma unroll
            for (int u = 0; u < 4; ++u)
                st[u] = Bbuf[(size_t)(ks + 1) * 1024 + tid + 256 * u];
        }
        bf16x8 af = *reinterpret_cast<const bf16x8*>(
            Abuf + ((size_t)strip * NKS + ks) * 64 + lane);
        #pragma unroll
        for (int nt = 0; nt < NNT; ++nt) {
            bf16x8 bfr = *reinterpret_cast<const bf16x8*>(&Bls[cur][nt * 64 + lane]);
            acc[nt] = __builtin_amdgcn_mfma_f32_16x16x32_bf16(af, bfr, acc[nt], 0, 0, 0);
        }
        if (ks < NKS - 1) {
            #pragma unroll
            for (int u = 0; u < 4; ++u) Bls[cur ^ 1][tid + 256 * u] = st[u];
        }
        __syncthreads();
    }

    // ---- epilogue: +bias, write h (f32), per-block column stats ----
    const int col16 = lane & 15, rg = lane >> 4;
    const int rowb = strip * 16 + rg * 4;
    float s_[NNT], q_[NNT];
    #pragma unroll
    for (int nt = 0; nt < NNT; ++nt) {
        float bn = b1[nt * 16 + col16];
        float s = 0.f, q = 0.f;
        #pragma unroll
        for (int r = 0; r < 4; ++r) {
            acc[nt][r] += bn;
            hbuf[(size_t)(rowb + r) * CO + nt * 16 + col16] = acc[nt][r];
            s += acc[nt][r];
            q += acc[nt][r] * acc[nt][r];
        }
        s += __shfl_xor(s, 16); s += __shfl_xor(s, 32);
        q += __shfl_xor(q, 16); q += __shfl_xor(q, 32);
        s_[nt] = s; q_[nt] = q;
    }
    float* S = reinterpret_cast<float*>(&Bls[0][0]);
    if (lane < 16) {
        #pragma unroll
        for (int nt = 0; nt < NNT; ++nt) {
            S[wave * 256 + nt * 16 + lane]        = s_[nt];
            S[1024 + wave * 256 + nt * 16 + lane] = q_[nt];
        }
    }
    __syncthreads();
    {
        float s = S[tid] + S[256 + tid] + S[512 + tid] + S[768 + tid];
        float q = S[1024 + tid] + S[1280 + tid] + S[1536 + tid] + S[1792 + tid];
        psum[(size_t)blk * CO + tid] = s;   // [block][channel], coalesced
        psq [(size_t)blk * CO + tid] = q;
    }
    __threadfence();
    if (tid == 0) lastFlag = (atomicAdd(counter, 1) == 255);
    __syncthreads();
    if (!lastFlag) return;
    __threadfence();   // acquire: all blocks' partials now visible

    // ---- last block: reduce partials -> scale/shift ----
    f32x4 sv = (f32x4)(0.f), qv = (f32x4)(0.f);
    for (int b = wave * 64; b < wave * 64 + 64; ++b) {
        float4 s4 = *reinterpret_cast<const float4*>(psum + (size_t)b * CO + lane * 4);
        float4 q4 = *reinterpret_cast<const float4*>(psq  + (size_t)b * CO + lane * 4);
        sv.x += s4.x; sv.y += s4.y; sv.z += s4.z; sv.w += s4.w;
        qv.x += q4.x; qv.y += q4.y; qv.z += q4.z; qv.w += q4.w;
    }
    #pragma unroll
    for (int u = 0; u < 4; ++u) {
        SQ[wave][lane * 4 + u]     = sv[u];
        SQ[4 + wave][lane * 4 + u] = qv[u];
    }
    __syncthreads();
    {
        float Sv = (SQ[0][tid] + SQ[1][tid]) + (SQ[2][tid] + SQ[3][tid]);
        float Qv = (SQ[4][tid] + SQ[5][tid]) + (SQ[6][tid] + SQ[7][tid]);
        float mean = Sv / NYF;
        float var  = Qv / NYF - mean * mean;
        float rstd = rsqrtf(var + 1e-6f);
        float sc = gamma[tid] * rstd;
        sscale[tid]       = sc;
        sscale[256 + tid] = beta[tid] - mean * sc;
    }
}

// K4: BN apply + LeakyReLU over h, in place (float4, grid-stride).
__global__ void k_final(float* __restrict__ h, const float* __restrict__ sscale,
                        int total4) {
    for (int t = blockIdx.x * blockDim.x + threadIdx.x; t < total4;
         t += gridDim.x * blockDim.x) {
        int c4 = (t & (CO / 4 - 1)) * 4;
        float4 v  = *reinterpret_cast<float4*>(h + (size_t)t * 4);
        float4 sc = *reinterpret_cast<const float4*>(sscale + c4);
        float4 sh = *reinterpret_cast<const float4*>(sscale + 256 + c4);
        v.x = v.x * sc.x + sh.x; v.x = v.x > 0.f ? v.x : 0.2f * v.x;
        v.y = v.y * sc.y + sh.y; v.y = v.y > 0.f ? v.y : 0.2f * v.y;
        v.z = v.z * sc.z + sh.z; v.z = v.z > 0.f ? v.z : 0.2f * v.z;
        v.w = v.w * sc.w + sh.w; v.w = v.w > 0.f ? v.w : 0.2f * v.w;
        *reinterpret_cast<float4*>(h + (size_t)t * 4) = v;
    }
}

extern "C" void kernel_launch(void* const* d_in, const int* in_sizes, int n_in,
                              void* d_out, int out_size, void* d_ws, size_t ws_size,
                              hipStream_t stream) {
    const float* x         = (const float*)d_in[0];
    const float* pos       = (const float*)d_in[1];
    const int*   batch     = (const int*)d_in[2];
    const float* x_skip    = (const float*)d_in[3];
    const float* pos_skip  = (const float*)d_in[4];
    const int*   batch_skip= (const int*)d_in[5];
    const float* w_att     = (const float*)d_in[6];
    const float* W1        = (const float*)d_in[7];
    const float* b1        = (const float*)d_in[8];
    const float* gamma     = (const float*)d_in[9];
    const float* beta      = (const float*)d_in[10];

    const int Nx = in_sizes[2];      // 4096
    const int Ny = in_sizes[5];      // 16384
    const int NB = 8;
    const int strips = Ny / 16;      // 1024

    char* w = (char*)d_ws;
    uint4*  Abuf     = (uint4*)w;  w += (size_t)strips * NKS * 64 * 16;   // 12.6 MB
    uint4*  Bbuf     = (uint4*)w;  w += (size_t)NKS * NNT * 64 * 16;      // 196 KB
    float4* pos4     = (float4*)w; w += (size_t)(Nx + 64) * 16;
    float*  attv     = (float*)w;  w += (size_t)Nx * 4;
    float*  psum     = (float*)w;  w += (size_t)256 * CO * 4;
    float*  psq      = (float*)w;  w += (size_t)256 * CO * 4;
    float*  sscale   = (float*)w;  w += (size_t)512 * 4;
    int*    counter  = (int*)w;    w += 64;
    int*    start    = (int*)w;    w += 64;

    float* outp = (float*)d_out;
    float* hbuf = outp;                                   // [Ny][Co] f32
    float4* out_tail4 = (float4*)(outp + (size_t)Ny * CO);
    const float4* pos_skip4 = (const float4*)pos_skip;
    const int4*   batch4    = (const int4*)batch_skip;

    const int total4 = Ny * CO / 4;

    k_prep<<<dim3(Nx / 4 + 49 + 64), dim3(256), 0, stream>>>(
        x, pos, w_att, W1, batch, attv, pos4, Bbuf, start, counter,
        pos_skip4, batch4, out_tail4, Nx, NB);
    k_knn<<<dim3(Ny / 16), dim3(256), 0, stream>>>(
        pos4, attv, pos_skip, batch_skip, start, x, x_skip, Abuf, Ny);
    k_gemm<<<dim3(Ny / 64), dim3(256), 0, stream>>>(
        Abuf, Bbuf, b1, gamma, beta, hbuf, psum, psq, sscale, counter);
    k_final<<<dim3(2048), dim3(256), 0, stream>>>(hbuf, sscale, total4);
}

// Round 9
// 73.905 us; speedup vs baseline: 1.3760x; 1.3760x over previous
//
#include <hip/hip_runtime.h>
#include <math.h>

// ---------------------------------------------------------------------------
// AttentiveFPModule: knn(K=3) attentive interpolate + concat + Linear + BN + LeakyReLU
// Sizes: Nx=4096, Ny=16384, C=256, Cs=128, Co=256, B=4, Kin=384
// 5 launches:
//   k_prep : attv/pos4/Bbuf fragments/start/tail outputs
//   k_knn  : knn scan (LDS-staged) + fused gather -> Abuf (MFMA A-fragments)
//   k_gemm : barrier-free MFMA (8 waves/block, A/B frags straight from global)
//   k_stats: reduce per-block partials -> BN scale/shift
//   k_final: BN apply + LeakyReLU in place
// Lesson R8: the MFMA kernel needs OCCUPANCY (>=8 waves/CU) and a barrier-free
// inner loop far more than it needs LDS-staged B; 1 wave/SIMD + per-ks
// barriers left the machine 97% idle regardless of where the gather lived.
// ---------------------------------------------------------------------------

#define KNEI 3
#define GL 16           // lanes per y-point in k_knn
#define UNR 4           // scan unroll
#define KCAP 2048       // staged pos4 capacity (float4s)
#define CIN 256         // C
#define CSK 128         // Cs
#define CO  256         // Co
#define NKS 12          // Kin / 32
#define NNT 16          // Co / 16
#define NYF 16384.0f
#define NPOS4 12288     // Ny*3/4
#define NTAIL4 16384    // NPOS4 + Ny/4

typedef __attribute__((ext_vector_type(8))) short bf16x8;
typedef __attribute__((ext_vector_type(4))) float f32x4;

__device__ __forceinline__ ushort f2bf(float f) {
    unsigned u = __float_as_uint(f);
    u += 0x7fffu + ((u >> 16) & 1u);
    return (ushort)(u >> 16);
}

__device__ __forceinline__ bool nless(float da, int ia, float db, int ib) {
    return (da < db) || (da == db && ia < ib);
}

__device__ __forceinline__ void ins3f(float dd, int j,
                                      float& d0, int& i0,
                                      float& d1, int& i1,
                                      float& d2, int& i2) {
    bool l0 = dd < d0;
    bool l1 = dd < d1;
    bool l2 = dd < d2;
    float n2 = l1 ? d1 : (l2 ? dd : d2); int m2 = l1 ? i1 : (l2 ? j : i2);
    float n1 = l0 ? d0 : (l1 ? dd : d1); int m1 = l0 ? i0 : (l1 ? j : i1);
    float n0 = l0 ? dd : d0;             int m0 = l0 ? j  : i0;
    d0 = n0; i0 = m0; d1 = n1; i1 = m1; d2 = n2; i2 = m2;
}

__device__ __forceinline__ void ins3t(float dd, int j,
                                      float& d0, int& i0,
                                      float& d1, int& i1,
                                      float& d2, int& i2) {
    bool l0 = nless(dd, j, d0, i0);
    bool l1 = nless(dd, j, d1, i1);
    bool l2 = nless(dd, j, d2, i2);
    float n2 = l1 ? d1 : (l2 ? dd : d2); int m2 = l1 ? i1 : (l2 ? j : i2);
    float n1 = l0 ? d0 : (l1 ? dd : d1); int m1 = l0 ? i0 : (l1 ? j : i1);
    float n0 = l0 ? dd : d0;             int m0 = l0 ? j  : i0;
    d0 = n0; i0 = m0; d1 = n1; i1 = m1; d2 = n2; i2 = m2;
}

// K1 (multi-role by block range):
//   [0, Nx/4)         : attv[j] = x[j].w_att ; pos4[j] = (pos, |pos|^2)
//   [Nx/4, Nx/4+48)   : W1 -> Bbuf MFMA B-fragments (bf16)
//   Nx/4+48           : start[] lower bounds; pos4 pad
//   [Nx/4+49, +49+64) : tail outputs (pos_skip copy, batch_skip as float)
__global__ void k_prep(const float* __restrict__ x, const float* __restrict__ pos,
                       const float* __restrict__ w_att, const float* __restrict__ W1,
                       const int* __restrict__ batch,
                       float* __restrict__ attv, float4* __restrict__ pos4,
                       uint4* __restrict__ Bbuf, int* __restrict__ start,
                       const float4* __restrict__ pos_skip4,
                       const int4* __restrict__ batch4,
                       float4* __restrict__ out_tail4,
                       int Nx, int NB) {
    int nb_x = Nx >> 2;
    int bid = blockIdx.x;
    int wave = threadIdx.x >> 6;
    int lane = threadIdx.x & 63;

    if (bid < nb_x) {
        int wid = bid * 4 + wave;
        float s = 0.f;
        for (int k = lane * 4; k < CIN; k += 256) {
            float4 xv = *reinterpret_cast<const float4*>(x + (size_t)wid * CIN + k);
            float4 wv = *reinterpret_cast<const float4*>(w_att + k);
            s += xv.x * wv.x + xv.y * wv.y + xv.z * wv.z + xv.w * wv.w;
        }
        #pragma unroll
        for (int off = 32; off; off >>= 1) s += __shfl_xor(s, off);
        if (lane == 0) {
            attv[wid] = s;
            float px = pos[wid * 3], py = pos[wid * 3 + 1], pz = pos[wid * 3 + 2];
            pos4[wid] = make_float4(px, py, pz, px * px + py * py + pz * pz);
        }
        return;
    }
    if (bid < nb_x + 48) {
        // Bbuf[(ks*16+nt)*64 + lane] = 8 bf16: elem j = W1[ks*32+(lane>>4)*8+j][nt*16+(lane&15)]
        int p  = (bid - nb_x) * 4 + wave;      // 0..191
        int ks = p >> 4, nt = p & 15;
        int kb = ks * 32 + (lane >> 4) * 8;
        int n  = nt * 16 + (lane & 15);
        ushort u[8];
        #pragma unroll
        for (int j = 0; j < 8; ++j)
            u[j] = f2bf(W1[(size_t)(kb + j) * CO + n]);
        uint4 o;
        o.x = (unsigned)u[0] | ((unsigned)u[1] << 16);
        o.y = (unsigned)u[2] | ((unsigned)u[3] << 16);
        o.z = (unsigned)u[4] | ((unsigned)u[5] << 16);
        o.w = (unsigned)u[6] | ((unsigned)u[7] << 16);
        Bbuf[(size_t)(ks * 16 + nt) * 64 + lane] = o;
        return;
    }
    if (bid == nb_x + 48) {
        int t = threadIdx.x;
        if (t < 64) {
            int b = t;
            if (b > NB) return;
            int lo = 0, hi = Nx;
            while (lo < hi) {
                int mid = (lo + hi) >> 1;
                if (batch[mid] < b) lo = mid + 1; else hi = mid;
            }
            start[b] = lo;
        } else if (t < 128) {
            pos4[Nx + (t - 64)] = make_float4(0.f, 0.f, 0.f, 0.f);
        }
        return;
    }
    // tail outputs
    int gid = (bid - (nb_x + 49)) * 256 + threadIdx.x;
    if (gid < NPOS4) {
        out_tail4[gid] = pos_skip4[gid];
    } else if (gid < NTAIL4) {
        int4 b4 = batch4[gid - NPOS4];
        out_tail4[gid] = make_float4((float)b4.x, (float)b4.y, (float)b4.z, (float)b4.w);
    }
}

// K2: 16 y-points per block (16 lanes each). knn scan (LDS-staged pos4
// segment) -> butterfly -> coef -> fused gather: block writes its 16 rows of
// A=[y||x_skip] into Abuf in MFMA A-fragment layout (bf16). 1024 blocks.
__global__ __launch_bounds__(256) void k_knn(
                      const float4* __restrict__ pos4,
                      const float* __restrict__ attv,
                      const float* __restrict__ pos_skip,
                      const int* __restrict__ batch_skip,
                      const int* __restrict__ start,
                      const float* __restrict__ x,
                      const float* __restrict__ x_skip,
                      uint4* __restrict__ Abuf, int Ny) {
    __shared__ float4 seg[KCAP + 64];
    __shared__ float coefL[16][3];
    __shared__ int   idxL[16][3];
    const int tid = threadIdx.x;
    int i16 = tid >> 4;
    int i   = blockIdx.x * 16 + i16;
    int sub = tid & (GL - 1);

    float py0 = pos_skip[i * 3], py1 = pos_skip[i * 3 + 1], py2 = pos_skip[i * 3 + 2];
    int bb = batch_skip[i];
    int s = start[bb], e = start[bb + 1];
    float ysq = py0 * py0 + py1 * py1 + py2 * py2;

    // block-uniform staging decision
    int b_first = batch_skip[blockIdx.x * 16];
    int b_last  = batch_skip[blockIdx.x * 16 + 15];
    int s0 = start[b_first];
    int span = start[b_last + 1] - s0;
    bool staged = (span <= KCAP);
    if (staged) {
        for (int t = tid; t < span; t += 256) seg[t] = pos4[s0 + t];
        __syncthreads();
    }

    const float FBIG = 3.38e38f;
    float a0 = __int_as_float(0x7f800000), a1 = a0, a2 = a0;
    float b0 = a0, b1v = a0, b2 = a0;
    int   ia0 = 0x7fffffff, ia1 = 0x7fffffff, ia2 = 0x7fffffff;
    int   ib0 = 0x7fffffff, ib1 = 0x7fffffff, ib2 = 0x7fffffff;

    if (staged) {
        for (int jb = s + sub; jb < e; jb += GL * UNR) {
            int j0 = jb, j1 = jb + GL, j2 = jb + 2 * GL, j3 = jb + 3 * GL;
            float4 v0 = seg[j0 - s0];
            float4 v1 = seg[j1 - s0];
            float4 v2 = seg[j2 - s0];
            float4 v3 = seg[j3 - s0];
            float t0 = fmaf(py2, v0.z, fmaf(py1, v0.y, py0 * v0.x));
            float t1 = fmaf(py2, v1.z, fmaf(py1, v1.y, py0 * v1.x));
            float t2 = fmaf(py2, v2.z, fmaf(py1, v2.y, py0 * v2.x));
            float t3 = fmaf(py2, v3.z, fmaf(py1, v3.y, py0 * v3.x));
            float dd0 = fmaf(-2.f, t0, ysq + v0.w);
            float dd1 = fmaf(-2.f, t1, ysq + v1.w);
            float dd2 = fmaf(-2.f, t2, ysq + v2.w);
            float dd3 = fmaf(-2.f, t3, ysq + v3.w);
            dd1 = (j1 < e) ? dd1 : FBIG;
            dd2 = (j2 < e) ? dd2 : FBIG;
            dd3 = (j3 < e) ? dd3 : FBIG;
            ins3f(dd0, j0, a0, ia0, a1, ia1, a2, ia2);
            ins3f(dd1, j1, b0, ib0, b1v, ib1, b2, ib2);
            ins3f(dd2, j2, a0, ia0, a1, ia1, a2, ia2);
            ins3f(dd3, j3, b0, ib0, b1v, ib1, b2, ib2);
        }
    } else {
        for (int jb = s + sub; jb < e; jb += GL * UNR) {
            int j0 = jb, j1 = jb + GL, j2 = jb + 2 * GL, j3 = jb + 3 * GL;
            float4 v0 = pos4[j0];
            float4 v1 = pos4[j1];
            float4 v2 = pos4[j2];
            float4 v3 = pos4[j3];
            float t0 = fmaf(py2, v0.z, fmaf(py1, v0.y, py0 * v0.x));
            float t1 = fmaf(py2, v1.z, fmaf(py1, v1.y, py0 * v1.x));
            float t2 = fmaf(py2, v2.z, fmaf(py1, v2.y, py0 * v2.x));
            float t3 = fmaf(py2, v3.z, fmaf(py1, v3.y, py0 * v3.x));
            float dd0 = fmaf(-2.f, t0, ysq + v0.w);
            float dd1 = fmaf(-2.f, t1, ysq + v1.w);
            float dd2 = fmaf(-2.f, t2, ysq + v2.w);
            float dd3 = fmaf(-2.f, t3, ysq + v3.w);
            dd1 = (j1 < e) ? dd1 : FBIG;
            dd2 = (j2 < e) ? dd2 : FBIG;
            dd3 = (j3 < e) ? dd3 : FBIG;
            ins3f(dd0, j0, a0, ia0, a1, ia1, a2, ia2);
            ins3f(dd1, j1, b0, ib0, b1v, ib1, b2, ib2);
            ins3f(dd2, j2, a0, ia0, a1, ia1, a2, ia2);
            ins3f(dd3, j3, b0, ib0, b1v, ib1, b2, ib2);
        }
    }

    ins3t(b0, ib0, a0, ia0, a1, ia1, a2, ia2);
    ins3t(b1v, ib1, a0, ia0, a1, ia1, a2, ia2);
    ins3t(b2, ib2, a0, ia0, a1, ia1, a2, ia2);

    #pragma unroll
    for (int off = 1; off < GL; off <<= 1) {
        float e0 = __shfl_xor(a0, off), e1 = __shfl_xor(a1, off), e2 = __shfl_xor(a2, off);
        int   j0 = __shfl_xor(ia0, off), j1 = __shfl_xor(ia1, off), j2 = __shfl_xor(ia2, off);
        ins3t(e0, j0, a0, ia0, a1, ia1, a2, ia2);
        ins3t(e1, j1, a0, ia0, a1, ia1, a2, ia2);
        ins3t(e2, j2, a0, ia0, a1, ia1, a2, ia2);
    }

    if (sub == 0) {
        int   jj[3] = { ia0, ia1, ia2 };
        float w[3], a[3];
        #pragma unroll
        for (int t = 0; t < KNEI; ++t) {
            int j = (jj[t] == 0x7fffffff) ? 0 : jj[t];
            jj[t] = j;
            float4 v = pos4[j];
            float dx = v.x - py0;
            float dy = v.y - py1;
            float dz = v.z - py2;
            float sqd = dx * dx + dy * dy + dz * dz;
            w[t] = 1.f / fmaxf(sqd, 1e-16f);
            a[t] = attv[j];
        }
        float m  = fmaxf(a[0], fmaxf(a[1], a[2]));
        float e0s = expf(a[0] - m), e1s = expf(a[1] - m), e2s = expf(a[2] - m);
        float se  = e0s + e1s + e2s;
        float den = w[0] + w[1] + w[2];
        float inv = 1.f / (se * den);
        #pragma unroll
        for (int t = 0; t < KNEI; ++t) {
            idxL[i16][t]  = jj[t];
            coefL[i16][t] = w[t] * ((t == 0) ? e0s : (t == 1) ? e1s : e2s) * inv;
        }
    }
    __syncthreads();

    // ---- fused gather: write this block's 16 rows as A-fragments ----
    {
        const int row16 = tid & 15, p = tid >> 4;
        const int grow = blockIdx.x * 16 + row16;
        const int g0 = idxL[row16][0];
        const int g1 = idxL[row16][1];
        const int g2 = idxL[row16][2];
        const float c0 = coefL[row16][0];
        const float c1 = coefL[row16][1];
        const float c2 = coefL[row16][2];
        #pragma unroll
        for (int u = 0; u < 3; ++u) {
            const int cidx = p + 16 * u;        // 0..47
            const int k0 = cidx * 8;
            float v[8];
            if (k0 < CIN) {
                const float4* p0 = reinterpret_cast<const float4*>(x + (size_t)g0 * CIN + k0);
                const float4* p1 = reinterpret_cast<const float4*>(x + (size_t)g1 * CIN + k0);
                const float4* p2 = reinterpret_cast<const float4*>(x + (size_t)g2 * CIN + k0);
                #pragma unroll
                for (int h = 0; h < 2; ++h) {
                    float4 a = p0[h], b = p1[h], c = p2[h];
                    v[h * 4 + 0] = c0 * a.x + c1 * b.x + c2 * c.x;
                    v[h * 4 + 1] = c0 * a.y + c1 * b.y + c2 * c.y;
                    v[h * 4 + 2] = c0 * a.z + c1 * b.z + c2 * c.z;
                    v[h * 4 + 3] = c0 * a.w + c1 * b.w + c2 * c.w;
                }
            } else {
                const float4* ps = reinterpret_cast<const float4*>(
                    x_skip + (size_t)grow * CSK + (k0 - CIN));
                #pragma unroll
                for (int h = 0; h < 2; ++h) {
                    float4 a = ps[h];
                    v[h * 4 + 0] = a.x; v[h * 4 + 1] = a.y;
                    v[h * 4 + 2] = a.z; v[h * 4 + 3] = a.w;
                }
            }
            ushort uu[8];
            #pragma unroll
            for (int j = 0; j < 8; ++j) uu[j] = f2bf(v[j]);
            uint4 o;
            o.x = (unsigned)uu[0] | ((unsigned)uu[1] << 16);
            o.y = (unsigned)uu[2] | ((unsigned)uu[3] << 16);
            o.z = (unsigned)uu[4] | ((unsigned)uu[5] << 16);
            o.w = (unsigned)uu[6] | ((unsigned)uu[7] << 16);
            const int ks = cidx >> 2, kg = cidx & 3;
            Abuf[((size_t)blockIdx.x * NKS + ks) * 64 + row16 + 16 * kg] = o;
        }
    }
}

// K3: barrier-free MFMA GEMM. 256 blocks x 8 waves. Wave w handles
// strip = blk*4 + (w>>1), N-half = w&1 (8 nt tiles = 128 cols).
// A-frags and B-frags read straight from global (coalesced 1KB/wave; B is
// L1/L2-broadcast; each A-frag shared by 2 waves on the same CU).
// One barrier total, at the stats combine.
__global__ __launch_bounds__(512, 4) void k_gemm(
    const uint4* __restrict__ Abuf, const uint4* __restrict__ Bbuf,
    const float* __restrict__ b1, float* __restrict__ hbuf,
    float* __restrict__ psum, float* __restrict__ psq) {
    __shared__ float SS[8][128], QQ[8][128];
    const int tid = threadIdx.x;
    const int w = tid >> 6, lane = tid & 63;
    const int strip = blockIdx.x * 4 + (w >> 1);
    const int half = w & 1;

    f32x4 acc[8];
    #pragma unroll
    for (int nt = 0; nt < 8; ++nt) acc[nt] = (f32x4)(0.f);

    #pragma unroll
    for (int ks = 0; ks < NKS; ++ks) {
        bf16x8 af = *reinterpret_cast<const bf16x8*>(
            Abuf + ((size_t)strip * NKS + ks) * 64 + lane);
        #pragma unroll
        for (int nt = 0; nt < 8; ++nt) {
            bf16x8 bfr = *reinterpret_cast<const bf16x8*>(
                Bbuf + ((size_t)(ks * 16 + half * 8 + nt)) * 64 + lane);
            acc[nt] = __builtin_amdgcn_mfma_f32_16x16x32_bf16(af, bfr, acc[nt], 0, 0, 0);
        }
    }

    // epilogue: +bias, write h (f32), per-wave column stats
    const int col16 = lane & 15, rg = lane >> 4;
    const int rowb = strip * 16 + rg * 4;
    float s_[8], q_[8];
    #pragma unroll
    for (int nt = 0; nt < 8; ++nt) {
        const int ntg = half * 8 + nt;
        float bn = b1[ntg * 16 + col16];
        float s = 0.f, q = 0.f;
        #pragma unroll
        for (int r = 0; r < 4; ++r) {
            float v = acc[nt][r] + bn;
            hbuf[(size_t)(rowb + r) * CO + ntg * 16 + col16] = v;
            s += v; q += v * v;
        }
        s += __shfl_xor(s, 16); s += __shfl_xor(s, 32);
        q += __shfl_xor(q, 16); q += __shfl_xor(q, 32);
        s_[nt] = s; q_[nt] = q;
    }
    if (lane < 16) {
        #pragma unroll
        for (int nt = 0; nt < 8; ++nt) {
            SS[w][nt * 16 + lane] = s_[nt];
            QQ[w][nt * 16 + lane] = q_[nt];
        }
    }
    __syncthreads();
    if (tid < 256) {
        int ch = tid;
        float s, q;
        if (ch < 128) {
            s = (SS[0][ch] + SS[2][ch]) + (SS[4][ch] + SS[6][ch]);
            q = (QQ[0][ch] + QQ[2][ch]) + (QQ[4][ch] + QQ[6][ch]);
        } else {
            int c = ch - 128;
            s = (SS[1][c] + SS[3][c]) + (SS[5][c] + SS[7][c]);
            q = (QQ[1][c] + QQ[3][c]) + (QQ[5][c] + QQ[7][c]);
        }
        psum[(size_t)blockIdx.x * CO + ch] = s;   // [block][channel], coalesced
        psq [(size_t)blockIdx.x * CO + ch] = q;
    }
}

// K4: reduce partials -> mean/var -> scale/shift per channel (1 block, 1024 thr)
__global__ void k_stats(const float* __restrict__ psum, const float* __restrict__ psq,
                        const float* __restrict__ gamma, const float* __restrict__ beta,
                        float* __restrict__ sscale, int mtiles, int Ny) {
    __shared__ float sred[4][256], qred[4][256];
    int c  = threadIdx.x & 255;
    int ch = threadIdx.x >> 8;
    int per = mtiles >> 2;
    float s = 0.f, q = 0.f;
    for (int m = ch * per; m < (ch + 1) * per; ++m) {
        s += psum[(size_t)m * CO + c];
        q += psq [(size_t)m * CO + c];
    }
    sred[ch][c] = s; qred[ch][c] = q;
    __syncthreads();
    if (ch == 0) {
        float S = ((sred[0][c] + sred[1][c]) + (sred[2][c] + sred[3][c]));
        float Q = ((qred[0][c] + qred[1][c]) + (qred[2][c] + qred[3][c]));
        float mean = S / (float)Ny;
        float var  = Q / (float)Ny - mean * mean;
        float rstd = rsqrtf(var + 1e-6f);
        float sc = gamma[c] * rstd;
        sscale[c]       = sc;
        sscale[256 + c] = beta[c] - mean * sc;
    }
}

// K5: BN apply + LeakyReLU over h, in place (float4, grid-stride).
__global__ void k_final(float* __restrict__ h, const float* __restrict__ sscale,
                        int total4) {
    for (int t = blockIdx.x * blockDim.x + threadIdx.x; t < total4;
         t += gridDim.x * blockDim.x) {
        int c4 = (t & (CO / 4 - 1)) * 4;
        float4 v  = *reinterpret_cast<float4*>(h + (size_t)t * 4);
        float4 sc = *reinterpret_cast<const float4*>(sscale + c4);
        float4 sh = *reinterpret_cast<const float4*>(sscale + 256 + c4);
        v.x = v.x * sc.x + sh.x; v.x = v.x > 0.f ? v.x : 0.2f * v.x;
        v.y = v.y * sc.y + sh.y; v.y = v.y > 0.f ? v.y : 0.2f * v.y;
        v.z = v.z * sc.z + sh.z; v.z = v.z > 0.f ? v.z : 0.2f * v.z;
        v.w = v.w * sc.w + sh.w; v.w = v.w > 0.f ? v.w : 0.2f * v.w;
        *reinterpret_cast<float4*>(h + (size_t)t * 4) = v;
    }
}

extern "C" void kernel_launch(void* const* d_in, const int* in_sizes, int n_in,
                              void* d_out, int out_size, void* d_ws, size_t ws_size,
                              hipStream_t stream) {
    const float* x         = (const float*)d_in[0];
    const float* pos       = (const float*)d_in[1];
    const int*   batch     = (const int*)d_in[2];
    const float* x_skip    = (const float*)d_in[3];
    const float* pos_skip  = (const float*)d_in[4];
    const int*   batch_skip= (const int*)d_in[5];
    const float* w_att     = (const float*)d_in[6];
    const float* W1        = (const float*)d_in[7];
    const float* b1        = (const float*)d_in[8];
    const float* gamma     = (const float*)d_in[9];
    const float* beta      = (const float*)d_in[10];

    const int Nx = in_sizes[2];      // 4096
    const int Ny = in_sizes[5];      // 16384
    const int NB = 8;
    const int strips  = Ny / 16;     // 1024
    const int gblocks = Ny / 64;     // 256

    char* w = (char*)d_ws;
    uint4*  Abuf     = (uint4*)w;  w += (size_t)strips * NKS * 64 * 16;   // 12.6 MB
    uint4*  Bbuf     = (uint4*)w;  w += (size_t)NKS * NNT * 64 * 16;      // 196 KB
    float4* pos4     = (float4*)w; w += (size_t)(Nx + 64) * 16;
    float*  attv     = (float*)w;  w += (size_t)Nx * 4;
    float*  psum     = (float*)w;  w += (size_t)gblocks * CO * 4;
    float*  psq      = (float*)w;  w += (size_t)gblocks * CO * 4;
    float*  sscale   = (float*)w;  w += (size_t)512 * 4;
    int*    start    = (int*)w;    w += 64;

    float* outp = (float*)d_out;
    float* hbuf = outp;                                   // [Ny][Co] f32
    float4* out_tail4 = (float4*)(outp + (size_t)Ny * CO);
    const float4* pos_skip4 = (const float4*)pos_skip;
    const int4*   batch4    = (const int4*)batch_skip;

    const int total4 = Ny * CO / 4;

    k_prep<<<dim3(Nx / 4 + 49 + 64), dim3(256), 0, stream>>>(
        x, pos, w_att, W1, batch, attv, pos4, Bbuf, start,
        pos_skip4, batch4, out_tail4, Nx, NB);
    k_knn<<<dim3(Ny / 16), dim3(256), 0, stream>>>(
        pos4, attv, pos_skip, batch_skip, start, x, x_skip, Abuf, Ny);
    k_gemm<<<dim3(gblocks), dim3(512), 0, stream>>>(
        Abuf, Bbuf, b1, hbuf, psum, psq);
    k_stats<<<dim3(1), dim3(1024), 0, stream>>>(
        psum, psq, gamma, beta, sscale, gblocks, Ny);
    k_final<<<dim3(2048), dim3(256), 0, stream>>>(hbuf, sscale, total4);
}